// Round 10
// baseline (141.750 us; speedup 1.0000x reference)
//
#include <hip/hip_runtime.h>

// Conv2d 3x3 VALID (NCHW/OIHW, fp32), fp16 MFMA, v6 "LDS-A + 4 chains".
// v4 skeleton (shift-GEMM, 128x128 sp tile, dbuf, 9 steps) +:
//  - A-slice (16KB/shift) staged to LDS via global_load_lds, double-buffered
//  - 256 thr = 4 waves; wave = 32cout x 128sp; acc[4] -> 4 MFMA chains, 16 MFMA/step
//  - LDS swizzle slot = oct ^ ((row>>1)&7): write conflict-free, read <=2-way

typedef __attribute__((ext_vector_type(8)))  _Float16 f16x8;
typedef __attribute__((ext_vector_type(16))) float    f32x16;

struct __attribute__((aligned(4))) f2u { float x, y; };

constexpr int C_IN = 64, H = 112, W = 112;
constexpr int COUT = 128, OH = 110, OW = 110;
constexpr int NIMG = 32;
constexpr int KTOT = C_IN * 9;            // 576
constexpr int OSP  = OH * OW;             // 12100
constexpr int SPTOT = NIMG * OSP;         // 387200 = 3025*128
constexpr int IMG_STRIDE = C_IN * H * W;
constexpr int CH_STRIDE  = H * W;         // 12544
constexpr int LDC = 72;                   // hw per sp-row (144B, 16B-aligned)
constexpr int ASLICE = 8 * COUT * 8;      // 8192 fp16 = 16KB per shift

__device__ __forceinline__ uint pkrtz_u32(float lo, float hi) {
    union { __fp16 __attribute__((ext_vector_type(2))) h; uint u; } c;
    c.h = __builtin_amdgcn_cvt_pkrtz(lo, hi);
    return c.u;
}

typedef __attribute__((address_space(3))) uint       lds_u32;
typedef __attribute__((address_space(1))) const uint glb_u32;

// A16[((s*8+o)*COUT + cout)*8 + j] = (f16)Kw[cout][(o*8+j)*9 + s]  (v4-verified)
__global__ void prep_a(const float* __restrict__ Kw, _Float16* __restrict__ A16) {
    int idx = blockIdx.x * 256 + threadIdx.x;
    if (idx >= COUT * KTOT) return;
    int cout = idx / KTOT, k = idx - cout * KTOT;
    int c = k / 9, s = k - c * 9;
    int o = c >> 3, j = c & 7;
    A16[((size_t)(s * 8 + o) * COUT + cout) * 8 + j] = (_Float16)Kw[idx];
}

__global__ __launch_bounds__(256, 2)
void conv_v6(const float* __restrict__ X,
             const _Float16* __restrict__ A16,
             float* __restrict__ Out)
{
    __shared__ __align__(16) _Float16 Bs[2][128 * LDC];  // 36864 B
    __shared__ __align__(16) _Float16 As[2][ASLICE];     // 32768 B

    const int t = threadIdx.x;

    // XCD-bijective block swizzle (m204); nwg=3025
    const int nwg = gridDim.x;
    const int q8 = nwg >> 3, r8 = nwg & 7;
    const int xcd = blockIdx.x & 7, idx8 = blockIdx.x >> 3;
    const int bid = (xcd < r8 ? xcd * (q8 + 1) : r8 * (q8 + 1) + (xcd - r8) * q8) + idx8;
    const int spBase = bid * 128;

    // ---- B staging: spp = sp-pair (cols 2spp,2spp+1), chh -> 16 channels ----
    const int spp = t & 63;
    const int chh = t >> 6;                   // 0..3
    const int sp0 = spBase + 2 * spp;
    const int nimg = sp0 / OSP;
    const int rsp  = sp0 - nimg * OSP;        // even
    const int oh   = rsp / OW;
    const int ow   = rsp - oh * OW;           // even
    const float* Xb = X + ((size_t)nimg * IMG_STRIDE + (size_t)(chh * 16) * CH_STRIDE + oh * W + ow);
    const int gsw = spp & 7;                  // (row>>1)&7 for both rows
    const int wr0 = (2 * spp) * LDC;
    const int wr1 = (2 * spp + 1) * LDC;

    // ---- compute mapping: 4 waves = 4 cout-quarters; wave = 32cout x 128sp ----
    const int lane  = t & 63;
    const int cq    = t >> 6;                 // wave id = cout quarter
    const int frow  = lane & 31;
    const int khalf = lane >> 5;
    const int bsw   = ((frow >> 1) & 7);      // read-side swizzle key

    f32x16 acc[4];
#pragma unroll
    for (int j = 0; j < 4; j++)
#pragma unroll
        for (int e = 0; e < 16; e++) acc[j][e] = 0.f;

    f2u g[16];

#define SOFF(S) (((S) / 3) * W + ((S) % 3))

#define GATHER(S)                                                              \
    {                                                                          \
        _Pragma("unroll")                                                      \
        for (int c = 0; c < 16; c++)                                           \
            g[c] = *reinterpret_cast<const f2u*>(Xb + (size_t)c * CH_STRIDE + SOFF(S)); \
    }

#define CVTWRITE(B)                                                            \
    {                                                                          \
        _Pragma("unroll")                                                      \
        for (int o = 0; o < 2; o++) {                                          \
            union { uint u[4]; f16x8 v; } px, py;                              \
            _Pragma("unroll")                                                  \
            for (int p = 0; p < 4; p++) {                                      \
                px.u[p] = pkrtz_u32(g[o * 8 + 2 * p].x, g[o * 8 + 2 * p + 1].x); \
                py.u[p] = pkrtz_u32(g[o * 8 + 2 * p].y, g[o * 8 + 2 * p + 1].y); \
            }                                                                  \
            const int slot = ((chh * 2 + o) ^ gsw) << 3;                       \
            *reinterpret_cast<f16x8*>(&Bs[B][wr0 + slot]) = px.v;              \
            *reinterpret_cast<f16x8*>(&Bs[B][wr1 + slot]) = py.v;              \
        }                                                                      \
    }

    // A-slice copy: 1024 x 16B units, unit idx = wave*256 + q*64 + lane (linear)
#define ACOPY(S, B)                                                            \
    {                                                                          \
        const _Float16* gsrc = A16 + (size_t)(S)*ASLICE;                       \
        _Pragma("unroll")                                                      \
        for (int q = 0; q < 4; q++) {                                          \
            const int unit = (cq * 4 + q) * 64 + lane;                         \
            __builtin_amdgcn_global_load_lds(                                  \
                (glb_u32*)(gsrc + unit * 8),                                   \
                (lds_u32*)(&As[B][unit * 8]), 16, 0, 0);                       \
        }                                                                      \
    }

#define MFMA_STEP(B)                                                           \
    {                                                                          \
        _Pragma("unroll")                                                      \
        for (int kk = 0; kk < 4; kk++) {                                       \
            const int oct = kk * 2 + khalf;                                    \
            const f16x8 a = *reinterpret_cast<const f16x8*>(                   \
                &As[B][(oct * COUT + cq * 32 + frow) * 8]);                    \
            _Pragma("unroll")                                                  \
            for (int j = 0; j < 4; j++) {                                      \
                const int slot = (oct ^ bsw) << 3;                             \
                const f16x8 b = *reinterpret_cast<const f16x8*>(               \
                    &Bs[B][(j * 32 + frow) * LDC + slot]);                     \
                acc[j] = __builtin_amdgcn_mfma_f32_32x32x16_f16(a, b, acc[j], 0, 0, 0); \
            }                                                                  \
        }                                                                      \
    }

    // ---- prologue: stage shift0 into buf0; gather shift1 ----
    GATHER(0);
    ACOPY(0, 0);
    CVTWRITE(0);
    GATHER(1);
    __syncthreads();   // drains gld_lds (vmcnt) + LDS writes

    // ---- main: 9 shifts, dbuf, one barrier/step ----
    // invariant at iter s: As/Bs[s&1] = shift s, g = shift s+1
#pragma unroll
    for (int s = 0; s < 9; s++) {
        if (s < 8) {
            ACOPY(s + 1, (s + 1) & 1);
            CVTWRITE((s + 1) & 1);
        }
        if (s < 7) GATHER(s + 2);
        MFMA_STEP(s & 1);
        __syncthreads();
    }

#undef GATHER
#undef CVTWRITE
#undef ACOPY
#undef MFMA_STEP
#undef SOFF

    // ---- store (v3-verified): D col=frow(sp), cout row=(reg&3)+8*(reg>>2)+4*khalf ----
    const int cbase = cq * 32 + 4 * khalf;
#pragma unroll
    for (int j = 0; j < 4; j++) {
        const int sp2 = spBase + j * 32 + frow;
        const int n2  = sp2 / OSP;
        const int r2  = sp2 - n2 * OSP;
        float* Ob = Out + (size_t)n2 * (COUT * (size_t)OSP) + r2;
#pragma unroll
        for (int reg = 0; reg < 16; reg++) {
            const int crow = cbase + (reg & 3) + 8 * (reg >> 2);
            Ob[(size_t)crow * OSP] = acc[j][reg];
        }
    }
}

extern "C" void kernel_launch(void* const* d_in, const int* in_sizes, int n_in,
                              void* d_out, int out_size, void* d_ws, size_t ws_size,
                              hipStream_t stream) {
    const float* X  = (const float*)d_in[0];
    const float* Kw = (const float*)d_in[1];
    float* Out = (float*)d_out;
    _Float16* A16 = (_Float16*)d_ws;    // 147456 B

    prep_a<<<(COUT * KTOT + 255) / 256, 256, 0, stream>>>(Kw, A16);
    conv_v6<<<SPTOT / 128, 256, 0, stream>>>(X, A16, Out);
}

// Round 11
// 109.900 us; speedup vs baseline: 1.2898x; 1.2898x over previous
//
#include <hip/hip_runtime.h>

// Conv2d 3x3 VALID (NCHW/OIHW, fp32), fp16 MFMA, v7 = v4 + A-register pipeline.
// v4 shift-GEMM skeleton (117us dispatch, proven): 128x128 sp tile, dense float2
// shift staging, LDS dbuf, 9 fully-unrolled steps, one barrier/step.
// NEW: A-fragments for step s+1 prefetched into named regs (aA/aB by step
// parity) during step s -> kills the serialized L2-load->MFMA chain that
// pinned MfmaUtil at ~20% with VGPR=60.

typedef __attribute__((ext_vector_type(8)))  _Float16 f16x8;
typedef __attribute__((ext_vector_type(16))) float    f32x16;

struct __attribute__((aligned(4))) f2u { float x, y; };

constexpr int C_IN = 64, H = 112, W = 112;
constexpr int COUT = 128, OH = 110, OW = 110;
constexpr int NIMG = 32;
constexpr int KTOT = C_IN * 9;            // 576
constexpr int OSP  = OH * OW;             // 12100
constexpr int SPTOT = NIMG * OSP;         // 387200 = 3025*128
constexpr int IMG_STRIDE = C_IN * H * W;
constexpr int CH_STRIDE  = H * W;         // 12544
constexpr int LDC = 72;                   // hw per sp-row (144B, 16B-aligned)

__device__ __forceinline__ uint pkrtz_u32(float lo, float hi) {
    union { __fp16 __attribute__((ext_vector_type(2))) h; uint u; } c;
    c.h = __builtin_amdgcn_cvt_pkrtz(lo, hi);
    return c.u;
}

// column-swizzled LDS halfword index (in-row bijective, bank-balanced)
__device__ __forceinline__ int swz(int row, int chw) {
    return row * LDC + (chw ^ (((row >> 1) & 7) << 3));
}

// A16[((s*8+o)*COUT + cout)*8 + j] = (f16)Kw[cout][(o*8+j)*9 + s]  (v4-verified)
__global__ void prep_a(const float* __restrict__ Kw, _Float16* __restrict__ A16) {
    int idx = blockIdx.x * 256 + threadIdx.x;
    if (idx >= COUT * KTOT) return;
    int cout = idx / KTOT, k = idx - cout * KTOT;
    int c = k / 9, s = k - c * 9;
    int o = c >> 3, j = c & 7;
    A16[((size_t)(s * 8 + o) * COUT + cout) * 8 + j] = (_Float16)Kw[idx];
}

__global__ __launch_bounds__(512, 4)
void conv_v7(const float* __restrict__ X,
             const _Float16* __restrict__ A16,
             float* __restrict__ Out)
{
    __shared__ __align__(16) _Float16 Bs[2][128 * LDC];   // 36864 B

    const int t = threadIdx.x;

    // XCD-bijective block swizzle (m204); nwg=3025
    const int nwg = gridDim.x;
    const int q8 = nwg >> 3, r8 = nwg & 7;
    const int xcd = blockIdx.x & 7, idx8 = blockIdx.x >> 3;
    const int bid = (xcd < r8 ? xcd * (q8 + 1) : r8 * (q8 + 1) + (xcd - r8) * q8) + idx8;
    const int spBase = bid * 128;

    // ---- staging: spp = sp-pair, c0 = 8-channel group (v4-identical) ----
    const int spp = t & 63;
    const int c0  = (t >> 6) << 3;
    const int sp0 = spBase + 2 * spp;
    const int nimg = sp0 / OSP;
    const int rsp  = sp0 - nimg * OSP;
    const int oh   = rsp / OW;
    const int ow   = rsp - oh * OW;
    const float* Xr = X + ((size_t)nimg * IMG_STRIDE + (size_t)c0 * CH_STRIDE + oh * W + ow);
    const int whw0 = swz(2 * spp,     c0);
    const int whw1 = swz(2 * spp + 1, c0);

    // ---- compute mapping (v4-identical): 8 waves = 4 cout-q x 2 sp-halves ----
    const int lane  = t & 63;
    const int wv    = t >> 6;
    const int wq    = wv >> 1;
    const int wc    = wv & 1;
    const int frow  = lane & 31;
    const int khalf = lane >> 5;
    const size_t arow = (size_t)(wq * 32 + frow) * 8;
    const int bmask = ((frow >> 1) & 7) << 3;
    const int brw0  = (wc * 64 + frow) * LDC;
    const int brw1  = (wc * 64 + 32 + frow) * LDC;

    f32x16 acc[2];
#pragma unroll
    for (int j = 0; j < 2; j++)
#pragma unroll
        for (int e = 0; e < 16; e++) acc[j][e] = 0.f;

    f2u g[8];
    f16x8 aA[4], aB[4];

#define SOFF(S) (((S) / 3) * W + ((S) % 3))

#define GATHER(S)                                                              \
    {                                                                          \
        _Pragma("unroll")                                                      \
        for (int j = 0; j < 8; j++)                                            \
            g[j] = *reinterpret_cast<const f2u*>(Xr + (size_t)j * CH_STRIDE + SOFF(S)); \
    }

#define CVTWRITE(BUF)                                                          \
    {                                                                          \
        union { uint u[4]; f16x8 v; } px, py;                                  \
        _Pragma("unroll")                                                      \
        for (int p = 0; p < 4; p++) {                                          \
            px.u[p] = pkrtz_u32(g[2 * p].x, g[2 * p + 1].x);                   \
            py.u[p] = pkrtz_u32(g[2 * p].y, g[2 * p + 1].y);                   \
        }                                                                      \
        *reinterpret_cast<f16x8*>(&Bs[BUF][whw0]) = px.v;                      \
        *reinterpret_cast<f16x8*>(&Bs[BUF][whw1]) = py.v;                      \
    }

#define ALOAD(DST, S)                                                          \
    {                                                                          \
        _Pragma("unroll")                                                      \
        for (int kk = 0; kk < 4; kk++)                                         \
            DST[kk] = *reinterpret_cast<const f16x8*>(                         \
                &A16[(size_t)(((S) * 8 + kk * 2 + khalf) * COUT) * 8 + arow]); \
    }

#define MFMA_STEP(B, AREG)                                                     \
    {                                                                          \
        _Pragma("unroll")                                                      \
        for (int kk = 0; kk < 4; kk++) {                                       \
            const int chw = (kk * 16 + khalf * 8) ^ bmask;                     \
            f16x8 b0 = *reinterpret_cast<const f16x8*>(&Bs[B][brw0 + chw]);    \
            f16x8 b1 = *reinterpret_cast<const f16x8*>(&Bs[B][brw1 + chw]);    \
            acc[0] = __builtin_amdgcn_mfma_f32_32x32x16_f16(AREG[kk], b0, acc[0], 0, 0, 0); \
            acc[1] = __builtin_amdgcn_mfma_f32_32x32x16_f16(AREG[kk], b1, acc[1], 0, 0, 0); \
        }                                                                      \
    }

    // one pipeline step: A(s+1)->NXT issued first, then B-tile s+1 write,
    // gather s+2, MFMA on s with CUR. Compile-time S -> all folds.
#define STEP(S, CUR, NXT)                                                      \
    {                                                                          \
        ALOAD(NXT, (S) + 1);                                                   \
        CVTWRITE(((S) + 1) & 1);                                               \
        if ((S) < 7) GATHER((S) + 2);                                          \
        MFMA_STEP((S) & 1, CUR);                                               \
        __syncthreads();                                                       \
    }

    // ---- prologue: regs <- A(0); buf0 <- shift0; g <- shift1 ----
    ALOAD(aA, 0);
    GATHER(0);
    CVTWRITE(0);
    GATHER(1);
    __syncthreads();

    // ---- 9 steps, explicit parity-named A pipeline ----
    STEP(0, aA, aB);
    STEP(1, aB, aA);
    STEP(2, aA, aB);
    STEP(3, aB, aA);
    STEP(4, aA, aB);
    STEP(5, aB, aA);
    STEP(6, aA, aB);
    STEP(7, aB, aA);
    MFMA_STEP(0, aA);   // s=8: Bs[0] holds shift 8; no further staging

#undef GATHER
#undef CVTWRITE
#undef ALOAD
#undef MFMA_STEP
#undef STEP
#undef SOFF

    // ---- store (v3-verified): D col=frow(sp), cout row=(reg&3)+8*(reg>>2)+4*khalf ----
#pragma unroll
    for (int j = 0; j < 2; j++) {
        const int sp2 = spBase + wc * 64 + j * 32 + frow;
        const int n2  = sp2 / OSP;
        const int r2  = sp2 - n2 * OSP;
        float* Ob = Out + (size_t)n2 * (COUT * (size_t)OSP) + r2;
        const int cbase = wq * 32 + 4 * khalf;
#pragma unroll
        for (int reg = 0; reg < 16; reg++) {
            const int crow = cbase + (reg & 3) + 8 * (reg >> 2);
            Ob[(size_t)crow * OSP] = acc[j][reg];
        }
    }
}

extern "C" void kernel_launch(void* const* d_in, const int* in_sizes, int n_in,
                              void* d_out, int out_size, void* d_ws, size_t ws_size,
                              hipStream_t stream) {
    const float* X  = (const float*)d_in[0];
    const float* Kw = (const float*)d_in[1];
    float* Out = (float*)d_out;
    _Float16* A16 = (_Float16*)d_ws;    // 147456 B

    prep_a<<<(COUT * KTOT + 255) / 256, 256, 0, stream>>>(Kw, A16);
    conv_v7<<<SPTOT / 128, 512, 0, stream>>>(X, A16, Out);
}